// Round 1
// baseline (484.334 us; speedup 1.0000x reference)
//
#include <hip/hip_runtime.h>

// MixConv: depthwise conv, 3 groups of 64 channels, k=3/5/7, same padding.
// x: [32,192,112,112] f32; w_k: [64,1,k,k] f32; out: [32,192,112,112] f32.
// Each thread computes 4 consecutive outputs along W (one float4).
// W=112 -> 28 float4 units/row; pad<=3<4 so each quad needs only the
// {left,mid,right} float4 per input row (zero vector at row edges).

#define N_BATCH 32
#define C_TOTAL 192
#define HW 112
#define WQ 28            // 112/4
#define UNITS_PER_PLANE (HW * WQ)  // 3136

template <int K>
__global__ __launch_bounds__(256) void mixconv_kernel(
    const float* __restrict__ x, const float* __restrict__ w,
    float* __restrict__ out, int cbase) {
  constexpr int PAD = (K - 1) / 2;

  const int c = blockIdx.y;  // 0..63 (uniform per block)
  const int n = blockIdx.z;  // 0..31

  // Block-uniform weight load -> scalar loads / SGPR broadcast.
  float wr[K * K];
#pragma unroll
  for (int i = 0; i < K * K; ++i) wr[i] = w[c * K * K + i];

  const int unit = blockIdx.x * 256 + threadIdx.x;
  if (unit >= UNITS_PER_PLANE) return;
  const int h = unit / WQ;
  const int wq = unit - h * WQ;

  const size_t plane = (size_t)(n * C_TOTAL + cbase + c) * (HW * HW);
  const float* xp = x + plane;

  float4 acc = {0.f, 0.f, 0.f, 0.f};

#pragma unroll
  for (int dy = 0; dy < K; ++dy) {
    const int ih = h + dy - PAD;
    if (ih < 0 || ih >= HW) continue;
    const float4* row = (const float4*)(xp + ih * HW);
    const float4 zero = {0.f, 0.f, 0.f, 0.f};
    float4 L = (wq > 0) ? row[wq - 1] : zero;
    float4 M = row[wq];
    float4 R = (wq < WQ - 1) ? row[wq + 1] : zero;
    // buf holds input cols [wq*4-4, wq*4+7]; fully static-indexed -> regs.
    float buf[12] = {L.x, L.y, L.z, L.w, M.x, M.y, M.z, M.w,
                     R.x, R.y, R.z, R.w};
#pragma unroll
    for (int dx = 0; dx < K; ++dx) {
      const float wv = wr[dy * K + dx];
      acc.x = fmaf(wv, buf[0 + dx + 4 - PAD], acc.x);
      acc.y = fmaf(wv, buf[1 + dx + 4 - PAD], acc.y);
      acc.z = fmaf(wv, buf[2 + dx + 4 - PAD], acc.z);
      acc.w = fmaf(wv, buf[3 + dx + 4 - PAD], acc.w);
    }
  }

  float4* orow =
      (float4*)(out + plane + (size_t)h * HW);
  orow[wq] = acc;
}

extern "C" void kernel_launch(void* const* d_in, const int* in_sizes, int n_in,
                              void* d_out, int out_size, void* d_ws,
                              size_t ws_size, hipStream_t stream) {
  const float* x = (const float*)d_in[0];
  const float* w3 = (const float*)d_in[1];
  const float* w5 = (const float*)d_in[2];
  const float* w7 = (const float*)d_in[3];
  float* out = (float*)d_out;

  const dim3 grid((UNITS_PER_PLANE + 255) / 256, 64, N_BATCH);
  const dim3 block(256);

  mixconv_kernel<3><<<grid, block, 0, stream>>>(x, w3, out, 0);
  mixconv_kernel<5><<<grid, block, 0, stream>>>(x, w5, out, 64);
  mixconv_kernel<7><<<grid, block, 0, stream>>>(x, w7, out, 128);
}